// Round 16
// baseline (2764.203 us; speedup 1.0000x reference)
//
#include <hip/hip_runtime.h>
#include <hip/hip_bf16.h>
#include <cstddef>
#include <cstdint>

#define B     64
#define S     256
#define E     640
#define H     512
#define TSTEPS (S - 1)       // 255
#define ZDIM  4096
#define KT    64
#define HS    (B * H)        // elems per state cell (32768)
#define CELL64 8192          // u64 units per h cell (64*512*2B / 8)
#define NBUF  4              // h rotation depth

// Dense flag layout: cells 0..3 at FSLOT (slot stride 16B, cell stride 512B);
// producer slots at u32 offset 512 + pslot*4 (16B stride), pslot=(d*32+tile)*2+half.
#define FSLOT(c, s) (((c) << 7) + ((s) << 2))   // u32 index

typedef __attribute__((ext_vector_type(8)))  __bf16 bf16x8;
typedef __attribute__((ext_vector_type(16))) float  f32x16;
typedef unsigned long long ull;

__device__ __forceinline__ float sigf(float x) { return 1.0f / (1.0f + __expf(-x)); }
__device__ __forceinline__ float tanhfast(float x) { return 1.0f - 2.0f / (__expf(2.0f * x) + 1.0f); }

__device__ __forceinline__ unsigned short f2bf(float f) {
    union { float f; unsigned u; } x; x.f = f;
    unsigned r = x.u + 0x7fffu + ((x.u >> 16) & 1u);   // RNE
    return (unsigned short)(r >> 16);
}
__device__ __forceinline__ float bf2f(unsigned short u) {
    union { unsigned u; float f; } x; x.u = ((unsigned)u) << 16;
    return x.f;
}
__device__ __forceinline__ unsigned pk2(float a, float b) {
    return (unsigned)f2bf(a) | ((unsigned)f2bf(b) << 16);
}
__device__ __forceinline__ uint4 pk8(float4 f0, float4 f1) {
    uint4 u;
    u.x = pk2(f0.x, f0.y); u.y = pk2(f0.z, f0.w);
    u.z = pk2(f1.x, f1.y); u.w = pk2(f1.z, f1.w);
    return u;
}

#define HSTORE64(p, v) __hip_atomic_store((p), (v), __ATOMIC_RELAXED, __HIP_MEMORY_SCOPE_AGENT)
#define HSTORE32(p, v) __hip_atomic_store((p), (v), __ATOMIC_RELAXED, __HIP_MEMORY_SCOPE_AGENT)

// Coherence-point plain loads (bypass L1+L2), pipelined.
__device__ __forceinline__ uint4 cld16(const void* p) {
    uint4 v;
    asm volatile("global_load_dwordx4 %0, %1, off sc0 sc1"
                 : "=v"(v) : "v"(p) : "memory");
    return v;
}
__device__ __forceinline__ unsigned ldf(const unsigned* p) {
    unsigned v;
    asm volatile("global_load_dword %0, %1, off sc0 sc1"
                 : "=v"(v) : "v"(p) : "memory");
    return v;
}
__device__ __forceinline__ void cwait0() {
    asm volatile("s_waitcnt vmcnt(0)" ::: "memory");
    __builtin_amdgcn_sched_barrier(0);
}
__device__ __forceinline__ void vmw16() {
    asm volatile("s_waitcnt vmcnt(16)" ::: "memory");
    __builtin_amdgcn_sched_barrier(0);
}
__device__ __forceinline__ bf16x8 u2b(uint4 u) {
    union { uint4 u; bf16x8 b; } x; x.u = u; return x.b;
}

// h-cell fragment layout (u64 granules): idx = wm*4096 + m*128 + khalf*64 + row*2 + plane
// lane fragment byte offset: wm*32768 + m*1024 + khalf*512 + (l&31)*16

// ---------------------------------------------------------------------------
// Prep kernels (XPRE=0 fallback only)
// ---------------------------------------------------------------------------
__global__ __launch_bounds__(256) void conv_x_kernel(
    const float* __restrict__ in, unsigned short* __restrict__ out, int n8)
{
    int i = blockIdx.x * 256 + threadIdx.x;
    if (i >= n8) return;
    const float4* p = (const float4*)(in + (size_t)i * 8);
    float4 a = p[0], b = p[1];
    unsigned short* o = out + (size_t)i * 8;
    o[0] = f2bf(a.x); o[1] = f2bf(a.y); o[2] = f2bf(a.z); o[3] = f2bf(a.w);
    o[4] = f2bf(b.x); o[5] = f2bf(b.y); o[6] = f2bf(b.z); o[7] = f2bf(b.w);
}

__global__ __launch_bounds__(256) void repack_w_kernel(
    const float* __restrict__ in, unsigned short* __restrict__ out, int K)
{
    int kc = K / 8;
    int i = blockIdx.x * 256 + threadIdx.x;
    if (i >= 2 * 2048 * kc) return;
    int k8 = i % kc;
    int n  = (i / kc) & 2047;
    int d  = i / (kc * 2048);
    int srow = (n & 3) * 512 + (n >> 2);
    const float* src = in + ((size_t)d * 2048 + srow) * K + (size_t)k8 * 8;
    unsigned short* dst = out + ((size_t)d * 2048 + n) * K + (size_t)k8 * 8;
    #pragma unroll
    for (int q = 0; q < 8; ++q) dst[q] = f2bf(src[q]);
}

__global__ __launch_bounds__(256) void pack_bias_kernel(
    const float* __restrict__ bih, const float* __restrict__ bhh, float* __restrict__ out)
{
    int i = blockIdx.x * 256 + threadIdx.x;   // 4096
    if (i >= 4096) return;
    int d = i >> 11, n = i & 2047;
    int s = d * 2048 + (n & 3) * 512 + (n >> 2);
    out[i] = bih[s] + bhh[s];
}

// ---------------------------------------------------------------------------
// Dense polls — wave0 only; caller does __syncthreads() after.
// ---------------------------------------------------------------------------
template<int XPRE>
__device__ __forceinline__ void poll_l0(const unsigned* flags, int d, int tile,
                                        unsigned traw, unsigned twar,
                                        unsigned tA, unsigned tB, int l)
{
    const unsigned* pd = flags + FSLOT(d, l & 31);
    const unsigned* pw = flags + FSLOT((l < 32) ? 2 : 3, l & 31);
    const unsigned* px = flags + 512 + (((d*32 + tile)*2 + (l & 1)) << 2);
    const unsigned tx = (l & 1) ? tB : tA;
    for (;;) {
        unsigned a = ldf(pd);
        unsigned b = ldf(pw);
        unsigned c = XPRE ? ldf(px) : 0xFFFFFFFFu;
        cwait0();
        bool ok = (a >= traw) && (b >= twar) && (l >= 2 || c >= tx);
        if (__all((int)ok)) break;
        __builtin_amdgcn_s_sleep(1);
    }
}
__device__ __forceinline__ void poll_l1(const unsigned* flags, int d,
                                        unsigned k, int l)
{
    const unsigned* po = flags + FSLOT(2 + d, l & 31);
    const unsigned* pc = flags + FSLOT((l < 32) ? 0 : 1, l & 31);
    const unsigned town = k - 1u;
    for (;;) {
        unsigned a = ldf(po);
        unsigned b = ldf(pc);
        cwait0();
        if (__all((int)(a >= town && b >= k))) break;
        __builtin_amdgcn_s_sleep(1);
    }
}

// ---------------------------------------------------------------------------
// L0 h-cell consumer + batched xp read (34 loads, single drain)
// ---------------------------------------------------------------------------
template<int XPRE>
__device__ __forceinline__ void hcell_l0(const void* hp, const void* xpp,
    const char* ldsrow, int rotofs, f32x16& a0, f32x16& a1,
    bf16x8& xpa, bf16x8& xpb)
{
    uint4 hv[32], xv0, xv1;
    if (XPRE) {
        xv0 = cld16(xpp);
        xv1 = cld16((const char*)xpp + 16);
    }
#pragma unroll
    for (int m = 0; m < 32; ++m)
        hv[m] = cld16((const char*)hp + (size_t)m * 1024);
    cwait0();
    if (XPRE) { xpa = u2b(xv0); xpb = u2b(xv1); }
#pragma unroll
    for (int m = 0; m < 32; ++m) {
        int o = (m*32 + rotofs) & 1023;
        bf16x8 b = *(const bf16x8*)(ldsrow + o);
        bf16x8 a = u2b(hv[m]);
        if (m & 1) a1 = __builtin_amdgcn_mfma_f32_32x32x16_bf16(a, b, a1, 0, 0, 0);
        else       a0 = __builtin_amdgcn_mfma_f32_32x32x16_bf16(a, b, a0, 0, 0, 0);
    }
}

// ---------------------------------------------------------------------------
// L1 pipelined mega-load helpers (16-load half-groups, counted vmcnt)
// ---------------------------------------------------------------------------
__device__ __forceinline__ void issue16(uint4* hv, const char* hpB, int mb) {
#pragma unroll
    for (int j = 0; j < 16; ++j)
        hv[j] = cld16(hpB + (size_t)(mb + j) * 1024);
}
__device__ __forceinline__ void consume16_reg(const uint4* hv, const bf16x8* wf,
                                              int mb, f32x16& a0, f32x16& a1)
{
#pragma unroll
    for (int j = 0; j < 16; ++j) {
        const int m = mb + j;
        bf16x8 a = u2b(hv[j]);
        if (m & 1) a1 = __builtin_amdgcn_mfma_f32_32x32x16_bf16(a, wf[m], a1, 0, 0, 0);
        else       a0 = __builtin_amdgcn_mfma_f32_32x32x16_bf16(a, wf[m], a0, 0, 0, 0);
    }
}
__device__ __forceinline__ void consume16_lds(const uint4* hv, const char* ldsrow,
                                              int rotofs, int mb, f32x16& a0, f32x16& a1)
{
#pragma unroll
    for (int j = 0; j < 16; ++j) {
        const int m = mb + j;
        int o = (m*32 + rotofs) & 2047;           // L1 ih rows are 2048B (pow2)
        bf16x8 b = *(const bf16x8*)(ldsrow + o);
        bf16x8 a = u2b(hv[j]);
        if (m & 1) a1 = __builtin_amdgcn_mfma_f32_32x32x16_bf16(a, b, a1, 0, 0, 0);
        else       a0 = __builtin_amdgcn_mfma_f32_32x32x16_bf16(a, b, a0, 0, 0, 0);
    }
}

// ---------------------------------------------------------------------------
// Activation + c/h-in-registers + coalesced fragment-order h store
// ---------------------------------------------------------------------------
template<bool XADD>
__device__ __forceinline__ void act_store(
    const f32x16& a0, const f32x16& a1, bf16x8 xpa, bf16x8 xpb,
    int unitg, int wm, int l, float* creg, float* hreg, ull* hq_cell)
{
    const int g  = l & 3;
    const int hi = l >> 5;
    union { bf16x8 v; unsigned short s[8]; } ua, ub;
    ua.v = xpa; ub.v = xpb;
    float gi[4], gf[4], gg[4], go[4];
#pragma unroll
    for (int r = 0; r < 16; ++r) {
        float v0 = a0[r] + a1[r];
        if (XADD) v0 += bf2f((r < 8) ? ua.s[r] : ub.s[r - 8]);
        float v1 = __shfl_xor(v0, 1);
        float v2 = __shfl_xor(v0, 2);
        float v3 = __shfl_xor(v0, 3);
        float pv[4] = {v0, v1, v2, v3};
        const int rg = r & 3, q = r >> 2;
        if (g == rg) { gi[q] = pv[rg^0]; gf[q] = pv[rg^1]; gg[q] = pv[rg^2]; go[q] = pv[rg^3]; }
    }
    const int ubase = unitg & ~3;
    ull* dst = hq_cell + wm*4096 + (ubase >> 4)*128 + ((ubase >> 3) & 1)*64
                       + ((ubase >> 2) & 1);
#pragma unroll
    for (int q = 0; q < 4; ++q) {
        int rl = g + 8*q + 4*hi;
        float cold = creg[q];
        float cnew = sigf(gf[q]) * cold + sigf(gi[q]) * tanhfast(gg[q]);
        float hnew = sigf(go[q]) * tanhfast(cnew);
        creg[q] = cnew;
        hreg[q] = hnew;
        unsigned m  = f2bf(hnew);
        unsigned o1 = __shfl_xor(m, 4);
        unsigned d0 = (unitg & 1) ? ((m << 16) | o1) : ((o1 << 16) | m);
        unsigned o2 = __shfl_xor(d0, 8);
        ull q64 = (unitg & 2) ? (((ull)d0 << 32) | (ull)o2) : (((ull)o2 << 32) | (ull)d0);
        if ((l & 12) == 0)
            HSTORE64(dst + rl*2, q64);
    }
}

// ---------------------------------------------------------------------------
// Persistent kernel. XPRE=1: 256 blocks — 64 L0, 64 L1, 128 xproj producers;
// all weight slices staged INLINE from original f32 tensors (no prep kernels).
// XPRE=0: 128 blocks (L0/L1 only, packed-buffer staging, conv_x'd xb).
// ---------------------------------------------------------------------------
template<int XPRE>
__global__ __launch_bounds__(256, 1) void persist_kernel(
    const float* __restrict__ xin,        // (S,B,E) f32
    const unsigned short* __restrict__ xb,
    const float* __restrict__ wih0f, const float* __restrict__ whh0f,
    const float* __restrict__ wih1f, const float* __restrict__ whh1f,
    const float* __restrict__ bih0,  const float* __restrict__ bhh0,
    const float* __restrict__ bih1,  const float* __restrict__ bhh1,
    const unsigned short* __restrict__ w0p,
    const unsigned short* __restrict__ wh0p,
    const unsigned short* __restrict__ w1p,
    const unsigned short* __restrict__ wh1p,
    const float* __restrict__ b0p,
    const float* __restrict__ b1p,
    unsigned short* __restrict__ xp,
    unsigned short* __restrict__ hbuf,
    float* __restrict__ cbuf,
    unsigned short* __restrict__ hplain,
    unsigned* __restrict__ flags)
{
    extern __shared__ __align__(16) char lds[];
    const int tid = threadIdx.x;
    const int l   = tid & 63;
    const int w   = tid >> 6;
    const int wm  = w & 1, wn = w >> 1;
    const int bid = blockIdx.x;
    const int lrow  = wn * 32 + (l & 31);
    const int khalf = l >> 5;
    const int HHOFF = 64 * 1280;

    // ================= PRODUCER ROLE (XPRE only, bid >= 128) ================
    if (XPRE && bid >= 128) {
        const int bid2 = bid - 128;
        const int dd   = bid2 >> 6;
        const int tile = (bid2 >> 1) & 31;
        const int half = bid2 & 1;
        const int n0p  = tile * 64;
        for (int idx = tid; idx < 64 * 80; idx += 256) {   // wih0 f32: 64 x 640
            int r = idx / 80, k8 = idx % 80;
            int srow = (((n0p + r) & 3) << 9) + ((n0p + r) >> 2);
            const float* src = wih0f + ((size_t)dd*2048 + srow)*640 + (size_t)k8*8;
            uint4 u = pk8(*(const float4*)src, *(const float4*)(src + 4));
            int o = k8*16 + r*16; o -= (o >= 1280) ? 1280 : 0;
            *(uint4*)(lds + r*1280 + o) = u;
        }
        __syncthreads();
        const char* ldsrow = lds + (size_t)lrow * 1280;
        const int rot = lrow * 16 + khalf * 16;
        const int t0 = half * 128, t1 = half ? TSTEPS : 128;
        unsigned* pxf = flags + 512 + (((dd*32 + tile)*2 + half) << 2);
        for (int t = t0; t < t1; ++t) {
            f32x16 a0, a1;
#pragma unroll
            for (int r = 0; r < 16; ++r) { a0[r] = 0.f; a1[r] = 0.f; }
            const float* Af = xin + ((size_t)t*B + wm*32 + (l & 31))*E + khalf*8;
#pragma unroll 8
            for (int k0 = 0; k0 < E; k0 += 16) {
                bf16x8 a = u2b(pk8(*(const float4*)(Af + k0), *(const float4*)(Af + k0 + 4)));
                int o = k0*2 + rot; o -= (o >= 1280) ? 1280 : 0;
                bf16x8 b = *(const bf16x8*)(ldsrow + o);
                if ((k0 >> 4) & 1) a1 = __builtin_amdgcn_mfma_f32_32x32x16_bf16(a, b, a1, 0, 0, 0);
                else               a0 = __builtin_amdgcn_mfma_f32_32x32x16_bf16(a, b, a0, 0, 0, 0);
            }
            size_t base = ((((size_t)t*2 + dd)*64 + tile*2 + wn)*2 + wm)*1024 + (size_t)l*16;
            ull* dst = (ull*)(xp + base);
            union { uint4 v; ull q[2]; } c0, c1;
            c0.v.x = pk2(a0[0]+a1[0],  a0[1]+a1[1]);
            c0.v.y = pk2(a0[2]+a1[2],  a0[3]+a1[3]);
            c0.v.z = pk2(a0[4]+a1[4],  a0[5]+a1[5]);
            c0.v.w = pk2(a0[6]+a1[6],  a0[7]+a1[7]);
            c1.v.x = pk2(a0[8]+a1[8],  a0[9]+a1[9]);
            c1.v.y = pk2(a0[10]+a1[10], a0[11]+a1[11]);
            c1.v.z = pk2(a0[12]+a1[12], a0[13]+a1[13]);
            c1.v.w = pk2(a0[14]+a1[14], a0[15]+a1[15]);
            HSTORE64(dst + 0, c0.q[0]); HSTORE64(dst + 1, c0.q[1]);
            HSTORE64(dst + 2, c1.q[0]); HSTORE64(dst + 3, c1.q[1]);
            asm volatile("s_waitcnt vmcnt(0)" ::: "memory");
            __syncthreads();
            if (tid == 0) HSTORE32(pxf, (unsigned)(t - t0 + 1));
        }
        return;
    }

    // ================= RECURRENCE ROLES =====================================
    const bool isL1 = bid >= 64;
    const int g2 = bid & 63;
    const int d  = g2 >> 5;
    const int n0 = (g2 & 31) * 64;
    const int myslot = g2 & 31;
    const int tile   = g2 & 31;

    if (XPRE) {
        if (!isL1) {
            for (int idx = tid; idx < 64 * 64; idx += 256) {   // whh0 f32: 64 x 512
                int r = idx >> 6, k8 = idx & 63;
                int srow = (((n0 + r) & 3) << 9) + ((n0 + r) >> 2);
                const float* src = whh0f + ((size_t)d*2048 + srow)*512 + (size_t)k8*8;
                uint4 u = pk8(*(const float4*)src, *(const float4*)(src + 4));
                int o = (k8*16 + r*16) & 1023;
                *(uint4*)(lds + r*1024 + o) = u;
            }
        } else {
            for (int idx = tid; idx < 64 * 128; idx += 256) {  // wih1 f32: 64 x 1024
                int r = idx >> 7, k8 = idx & 127;
                int srow = (((n0 + r) & 3) << 9) + ((n0 + r) >> 2);
                const float* src = wih1f + ((size_t)d*2048 + srow)*1024 + (size_t)k8*8;
                uint4 u = pk8(*(const float4*)src, *(const float4*)(src + 4));
                int o = (k8*16 + r*16) & 2047;
                *(uint4*)(lds + r*2048 + o) = u;
            }
        }
    } else {
        if (!isL1) {
            for (int idx = tid; idx < 64 * 80; idx += 256) {
                int r = idx / 80, k8 = idx % 80;
                bf16x8 v = *(const bf16x8*)(w0p + ((size_t)d*2048 + n0 + r)*640 + (size_t)k8*8);
                int o = k8*16 + r*16; o -= (o >= 1280) ? 1280 : 0;
                *(bf16x8*)(lds + r*1280 + o) = v;
            }
            for (int idx = tid; idx < 64 * 64; idx += 256) {
                int r = idx / 64, k8 = idx % 64;
                bf16x8 v = *(const bf16x8*)(wh0p + ((size_t)d*2048 + n0 + r)*512 + (size_t)k8*8);
                int o = k8*16 + r*16; o -= (o >= 1024) ? 1024 : 0;
                *(bf16x8*)(lds + HHOFF + r*1024 + o) = v;
            }
        } else {
            for (int idx = tid; idx < 64 * 128; idx += 256) {
                int r = idx / 128, k8 = idx % 128;
                bf16x8 v = *(const bf16x8*)(w1p + ((size_t)d*2048 + n0 + r)*1024 + (size_t)k8*8);
                int o = k8*16 + r*16; o -= (o >= 2048) ? 2048 : 0;
                *(bf16x8*)(lds + r*2048 + o) = v;
            }
        }
    }
    __syncthreads();

    const int srowg = (((n0 + lrow) & 3) << 9) + ((n0 + lrow) >> 2);
    const float bias = XPRE
        ? (isL1 ? (bih1[d*2048 + srowg] + bhh1[d*2048 + srowg])
                : (bih0[d*2048 + srowg] + bhh0[d*2048 + srowg]))
        : (isL1 ? b1p : b0p)[d*2048 + n0 + lrow];
    const char* ldsrow_ih = lds + (size_t)lrow * (isL1 ? 2048 : 1280);
    const char* ldsrow_hh = lds + (XPRE ? 0 : HHOFF) + (size_t)lrow * 1024;
    const int rot = lrow * 16 + khalf * 16;
    const int unitg = ((n0 + lrow) >> 2);
    const int hoff  = wm*4096 + khalf*64 + (l & 31)*2;     // u64 units
    const int arow  = wm * 32 + (l & 31);
    float creg[4] = {0.f, 0.f, 0.f, 0.f};
    float hreg[4] = {0.f, 0.f, 0.f, 0.f};
    const ull* hb = (const ull*)hbuf;
    ull*       hw = (ull*)hbuf;
    const int mycell = isL1 ? (2 + d) : d;
    unsigned* myflag = flags + FSLOT(mycell, myslot);
    bf16x8 zero8 = {};

    bf16x8 wh[32];     // L1: own-cell hidden weights in VGPR
    if (isL1) {
        if (XPRE) {
            const float* whl = whh1f + ((size_t)d*2048 + srowg)*512 + khalf*8;
#pragma unroll
            for (int m = 0; m < 32; ++m)
                wh[m] = u2b(pk8(*(const float4*)(whl + m*16), *(const float4*)(whl + m*16 + 4)));
        } else {
            const unsigned short* whl = wh1p + ((size_t)d*2048 + n0 + lrow)*512 + khalf*8;
#pragma unroll
            for (int m = 0; m < 32; ++m) wh[m] = *(const bf16x8*)(whl + m*16);
        }
    }

    for (int k = 0; k <= TSTEPS; ++k) {
        const int rbuf = k % NBUF, wbuf = (k + 1) % NBUF;
        const size_t rb = (size_t)rbuf * 4 * CELL64;
        const size_t wb = (size_t)wbuf * 4 * CELL64;
        if (!isL1) {
            if (k < TSTEPS) {
                f32x16 a0, a1;
#pragma unroll
                for (int r = 0; r < 16; ++r) { a0[r] = bias; a1[r] = 0.f; }
                bf16x8 xpa = zero8, xpb = zero8;
                if (!XPRE) {
                    const unsigned short* Ax = xb + (size_t)k*B*E + (size_t)arow*E + khalf*8;
#pragma unroll 8
                    for (int k0 = 0; k0 < E; k0 += 16) {
                        bf16x8 a = *(const bf16x8*)(Ax + k0);
                        int o = k0*2 + rot; o -= (o >= 1280) ? 1280 : 0;
                        bf16x8 b = *(const bf16x8*)(ldsrow_ih + o);
                        if ((k0 >> 4) & 1) a1 = __builtin_amdgcn_mfma_f32_32x32x16_bf16(a, b, a1, 0, 0, 0);
                        else               a0 = __builtin_amdgcn_mfma_f32_32x32x16_bf16(a, b, a0, 0, 0, 0);
                    }
                }
                {
                    unsigned tA = XPRE ? ((k < 128) ? (unsigned)(k + 1) : 128u) : 0u;
                    unsigned tB = XPRE ? ((k < 128) ? 0u : (unsigned)(k - 127)) : 0u;
                    unsigned traw = (k >= 1) ? (unsigned)k : 0u;
                    unsigned twar = (k >= 3) ? (unsigned)(k - 3) : 0u;
                    if (XPRE || k >= 1) {
                        if (w == 0) poll_l0<XPRE>(flags, d, tile, traw, twar, tA, tB, l);
                        __syncthreads();
                    }
                }
                const char* xpp = (const char*)xp +
                    (((((size_t)k*2 + d)*64 + tile*2 + wn)*2 + wm)*1024 + (size_t)l*16) * 2;
                hcell_l0<XPRE>((const char*)(hb + rb + (size_t)d*CELL64 + hoff), xpp,
                               ldsrow_hh, rot, a0, a1, xpa, xpb);
                act_store<true>(a0, a1, xpa, xpb, unitg, wm, l, creg, hreg,
                                hw + wb + (size_t)d*CELL64);
                asm volatile("s_waitcnt vmcnt(0)" ::: "memory");
                __syncthreads();                       // all waves' stores acked
                if (tid == 0) HSTORE32(myflag, (unsigned)(k + 1));
            }
        } else {
            if (k >= 1) {
                f32x16 a0, a1;
#pragma unroll
                for (int r = 0; r < 16; ++r) { a0[r] = bias; a1[r] = 0.f; }
                if (w == 0) poll_l1(flags, d, (unsigned)k, l);
                __syncthreads();
                const char* hpO = (const char*)(hb + rb + (size_t)(2+d)*CELL64 + hoff);
                const char* hp0 = (const char*)(hb + rb + (size_t)0*CELL64 + hoff);
                const char* hp1 = (const char*)(hb + rb + (size_t)1*CELL64 + hoff);
                uint4 hvA[16], hvB[16];
                issue16(hvA, hpO, 0);
                issue16(hvB, hpO, 16);
                vmw16(); consume16_reg(hvA, wh, 0,  a0, a1);
                issue16(hvA, hp0, 0);
                vmw16(); consume16_reg(hvB, wh, 16, a0, a1);
                issue16(hvB, hp0, 16);
                vmw16(); consume16_lds(hvA, ldsrow_ih, rot, 0,  a0, a1);
                issue16(hvA, hp1, 0);
                vmw16(); consume16_lds(hvB, ldsrow_ih, rot, 16, a0, a1);
                issue16(hvB, hp1, 16);
                vmw16(); consume16_lds(hvA, ldsrow_ih, rot + 1024, 0,  a0, a1);
                cwait0(); consume16_lds(hvB, ldsrow_ih, rot + 1024, 16, a0, a1);
                act_store<false>(a0, a1, zero8, zero8, unitg, wm, l, creg, hreg,
                                 hw + wb + (size_t)(2+d)*CELL64);
                asm volatile("s_waitcnt vmcnt(0)" ::: "memory");
                __syncthreads();
                if (tid == 0) HSTORE32(myflag, (unsigned)k);
            }
        }
    }

    {
        float*          cc = cbuf   + (size_t)mycell * HS;
        unsigned short* hh = hplain + (size_t)mycell * HS;
        const int g = l & 3, hi = l >> 5;
#pragma unroll
        for (int q = 0; q < 4; ++q) {
            int row = 32*wm + g + 8*q + 4*hi;
            cc[(size_t)row * 512 + unitg] = creg[q];
            hh[(size_t)row * 512 + unitg] = f2bf(hreg[q]);
        }
    }
}

// ---------------------------------------------------------------------------
// Head (unchanged)
// ---------------------------------------------------------------------------
__global__ __launch_bounds__(256) void head_kernel(
    const unsigned short* __restrict__ hplain,
    const float* __restrict__ cbuf,
    const float* __restrict__ eps,
    const float* __restrict__ Wmu,  const float* __restrict__ bmu,
    const float* __restrict__ Wvar, const float* __restrict__ bvar,
    float* __restrict__ out)
{
    const int tid = threadIdx.x;
    const int b   = tid & 63;
    const int i   = blockIdx.x * 4 + (tid >> 6);

    __shared__ float zs[KT][B + 1];

    float amu = 0.f, alv = 0.f;
    const float* wm = Wmu  + (size_t)i * ZDIM;
    const float* wv = Wvar + (size_t)i * ZDIM;

    for (int k0 = 0; k0 < ZDIM; k0 += KT) {
        __syncthreads();
        for (int idx = tid; idx < (B * KT) / 4; idx += 256) {
            int bb  = idx / (KT / 4);
            int kq4 = (idx % (KT / 4)) * 4;
            int zk  = k0 + kq4;
            int cell = zk >> 10;
            int m    = zk & 1023;
            float4 v;
            if (m < H) {
                const unsigned short* hs = hplain + (size_t)cell * HS + (size_t)bb * H + m;
                v.x = bf2f(hs[0]); v.y = bf2f(hs[1]); v.z = bf2f(hs[2]); v.w = bf2f(hs[3]);
            } else {
                v = *(const float4*)(cbuf + (size_t)cell * HS + (size_t)bb * H + (m - H));
            }
            zs[kq4 + 0][bb] = v.x; zs[kq4 + 1][bb] = v.y;
            zs[kq4 + 2][bb] = v.z; zs[kq4 + 3][bb] = v.w;
        }
        __syncthreads();
        #pragma unroll
        for (int kk = 0; kk < KT; kk += 4) {
            float4 a = *(const float4*)(wm + k0 + kk);
            float4 c = *(const float4*)(wv + k0 + kk);
            float z0 = zs[kk + 0][b], z1 = zs[kk + 1][b];
            float z2 = zs[kk + 2][b], z3 = zs[kk + 3][b];
            amu += a.x * z0 + a.y * z1 + a.z * z2 + a.w * z3;
            alv += c.x * z0 + c.y * z1 + c.z * z2 + c.w * z3;
        }
    }
    float mu = amu + bmu[i];
    float lv = alv + bvar[i];
    out[(size_t)b * ZDIM + i] = mu + eps[(size_t)b * ZDIM + i] * __expf(0.5f * lv);
}

// ---------------------------------------------------------------------------
extern "C" void kernel_launch(void* const* d_in, const int* in_sizes, int n_in,
                              void* d_out, int out_size, void* d_ws, size_t ws_size,
                              hipStream_t stream) {
    const float* input = (const float*)d_in[0];
    const float* eps   = (const float*)d_in[1];
    const float* w_ih0 = (const float*)d_in[2];
    const float* w_hh0 = (const float*)d_in[3];
    const float* b_ih0 = (const float*)d_in[4];
    const float* b_hh0 = (const float*)d_in[5];
    const float* w_ih1 = (const float*)d_in[6];
    const float* w_hh1 = (const float*)d_in[7];
    const float* b_ih1 = (const float*)d_in[8];
    const float* b_hh1 = (const float*)d_in[9];
    const float* W_mu  = (const float*)d_in[10];
    const float* b_mu  = (const float*)d_in[11];
    const float* W_var = (const float*)d_in[12];
    const float* b_var = (const float*)d_in[13];
    float* out = (float*)d_out;

    uint8_t* base = (uint8_t*)d_ws;
    size_t off = 0;
    auto alloc = [&](size_t bytes) -> void* {
        void* p = base + off;
        off += (bytes + 255) & ~(size_t)255;
        return p;
    };
    unsigned short* xb   = (unsigned short*)alloc((size_t)TSTEPS * B * E * 2);
    unsigned short* w0p  = (unsigned short*)alloc((size_t)2 * 2048 * E * 2);
    unsigned short* wh0p = (unsigned short*)alloc((size_t)2 * 2048 * H * 2);
    unsigned short* w1p  = (unsigned short*)alloc((size_t)2 * 2048 * 1024 * 2);
    unsigned short* wh1p = (unsigned short*)alloc((size_t)2 * 2048 * H * 2);
    float* b0p = (float*)alloc(2 * 2048 * 4);
    float* b1p = (float*)alloc(2 * 2048 * 4);
    unsigned* flags      = (unsigned*)alloc(4096);      // cells 2KB + producers 2KB
    unsigned short* hbuf = (unsigned short*)alloc((size_t)NBUF * 4 * HS * 2);
    float* cbuf          = (float*)alloc((size_t)4 * HS * 4);
    unsigned short* hplain = (unsigned short*)alloc((size_t)4 * HS * 2);
    unsigned short* xp   = (unsigned short*)alloc((size_t)TSTEPS * 2 * 2048 * B * 2); // 134MB
    const bool XPRE = (ws_size >= off);

    // zero flags + h (NBUF bufs)
    hipMemsetAsync(flags, 0, 4096 + (size_t)NBUF * 4 * HS * 2, stream);

    const size_t lds_persist = 144 * 1024;
    if (XPRE) {
        // no prep kernels: all weight staging is inline in persist
        hipFuncSetAttribute((const void*)persist_kernel<1>,
                            hipFuncAttributeMaxDynamicSharedMemorySize, (int)lds_persist);
        persist_kernel<1><<<256, 256, lds_persist, stream>>>(
            input, xb, w_ih0, w_hh0, w_ih1, w_hh1, b_ih0, b_hh0, b_ih1, b_hh1,
            w0p, wh0p, w1p, wh1p, b0p, b1p, xp, hbuf, cbuf, hplain, flags);
    } else {
        conv_x_kernel<<<(TSTEPS * B * E / 8 + 255) / 256, 256, 0, stream>>>(
            input, xb, TSTEPS * B * E / 8);
        repack_w_kernel<<<(2 * 2048 * (E / 8) + 255) / 256, 256, 0, stream>>>(w_ih0, w0p, E);
        repack_w_kernel<<<(2 * 2048 * (H / 8) + 255) / 256, 256, 0, stream>>>(w_hh0, wh0p, H);
        repack_w_kernel<<<(2 * 2048 * (1024 / 8) + 255) / 256, 256, 0, stream>>>(w_ih1, w1p, 1024);
        repack_w_kernel<<<(2 * 2048 * (H / 8) + 255) / 256, 256, 0, stream>>>(w_hh1, wh1p, H);
        pack_bias_kernel<<<16, 256, 0, stream>>>(b_ih0, b_hh0, b0p);
        pack_bias_kernel<<<16, 256, 0, stream>>>(b_ih1, b_hh1, b1p);
        hipFuncSetAttribute((const void*)persist_kernel<0>,
                            hipFuncAttributeMaxDynamicSharedMemorySize, (int)lds_persist);
        persist_kernel<0><<<128, 256, lds_persist, stream>>>(
            input, xb, w_ih0, w_hh0, w_ih1, w_hh1, b_ih0, b_hh0, b_ih1, b_hh1,
            w0p, wh0p, w1p, wh1p, b0p, b1p, xp, hbuf, cbuf, hplain, flags);
    }

    head_kernel<<<ZDIM / 4, 256, 0, stream>>>(hplain, cbuf, eps, W_mu, b_mu, W_var, b_var, out);
}

// Round 18
// 2751.441 us; speedup vs baseline: 1.0046x; 1.0046x over previous
//
#include <hip/hip_runtime.h>
#include <hip/hip_bf16.h>
#include <cstddef>
#include <cstdint>

#define B     64
#define S     256
#define E     640
#define H     512
#define TSTEPS (S - 1)       // 255
#define ZDIM  4096
#define KT    64
#define HS    (B * H)        // elems per state cell (32768)
#define CELL64 8192          // u64 units per h cell (64*512*2B / 8)
#define NBUF  4              // h rotation depth

// Dense flag layout: cells 0..3 at FSLOT (slot stride 16B, cell stride 512B);
// producer slots at u32 offset 512 + pslot*4 (16B stride).
#define FSLOT(c, s) (((c) << 7) + ((s) << 2))   // u32 index

typedef __attribute__((ext_vector_type(8)))  __bf16 bf16x8;
typedef __attribute__((ext_vector_type(16))) float  f32x16;
typedef unsigned long long ull;

__device__ __forceinline__ float sigf(float x) { return 1.0f / (1.0f + __expf(-x)); }
__device__ __forceinline__ float tanhfast(float x) { return 1.0f - 2.0f / (__expf(2.0f * x) + 1.0f); }

__device__ __forceinline__ unsigned short f2bf(float f) {
    union { float f; unsigned u; } x; x.f = f;
    unsigned r = x.u + 0x7fffu + ((x.u >> 16) & 1u);   // RNE
    return (unsigned short)(r >> 16);
}
__device__ __forceinline__ float bf2f(unsigned short u) {
    union { unsigned u; float f; } x; x.u = ((unsigned)u) << 16;
    return x.f;
}
__device__ __forceinline__ unsigned pk2(float a, float b) {
    return (unsigned)f2bf(a) | ((unsigned)f2bf(b) << 16);
}
__device__ __forceinline__ uint4 pk8(float4 f0, float4 f1) {
    uint4 u;
    u.x = pk2(f0.x, f0.y); u.y = pk2(f0.z, f0.w);
    u.z = pk2(f1.x, f1.y); u.w = pk2(f1.z, f1.w);
    return u;
}

#define HSTORE64(p, v) __hip_atomic_store((p), (v), __ATOMIC_RELAXED, __HIP_MEMORY_SCOPE_AGENT)
#define HSTORE32(p, v) __hip_atomic_store((p), (v), __ATOMIC_RELAXED, __HIP_MEMORY_SCOPE_AGENT)

// Coherence-point plain loads (bypass L1+L2), pipelined.
__device__ __forceinline__ uint4 cld16(const void* p) {
    uint4 v;
    asm volatile("global_load_dwordx4 %0, %1, off sc0 sc1"
                 : "=v"(v) : "v"(p) : "memory");
    return v;
}
__device__ __forceinline__ unsigned ldf(const unsigned* p) {
    unsigned v;
    asm volatile("global_load_dword %0, %1, off sc0 sc1"
                 : "=v"(v) : "v"(p) : "memory");
    return v;
}
__device__ __forceinline__ void cwait0() {
    asm volatile("s_waitcnt vmcnt(0)" ::: "memory");
    __builtin_amdgcn_sched_barrier(0);
}
__device__ __forceinline__ void vmw16() {
    asm volatile("s_waitcnt vmcnt(16)" ::: "memory");
    __builtin_amdgcn_sched_barrier(0);
}
__device__ __forceinline__ bf16x8 u2b(uint4 u) {
    union { uint4 u; bf16x8 b; } x; x.u = u; return x.b;
}

// h-cell fragment layout (u64 granules): idx = wm*4096 + m*128 + khalf*64 + row*2 + plane
// lane fragment byte offset: wm*32768 + m*1024 + khalf*512 + (l&31)*16

// ---------------------------------------------------------------------------
// Prep kernels (XPRE=0 fallback only)
// ---------------------------------------------------------------------------
__global__ __launch_bounds__(256) void conv_x_kernel(
    const float* __restrict__ in, unsigned short* __restrict__ out, int n8)
{
    int i = blockIdx.x * 256 + threadIdx.x;
    if (i >= n8) return;
    const float4* p = (const float4*)(in + (size_t)i * 8);
    float4 a = p[0], b = p[1];
    unsigned short* o = out + (size_t)i * 8;
    o[0] = f2bf(a.x); o[1] = f2bf(a.y); o[2] = f2bf(a.z); o[3] = f2bf(a.w);
    o[4] = f2bf(b.x); o[5] = f2bf(b.y); o[6] = f2bf(b.z); o[7] = f2bf(b.w);
}

__global__ __launch_bounds__(256) void repack_w_kernel(
    const float* __restrict__ in, unsigned short* __restrict__ out, int K)
{
    int kc = K / 8;
    int i = blockIdx.x * 256 + threadIdx.x;
    if (i >= 2 * 2048 * kc) return;
    int k8 = i % kc;
    int n  = (i / kc) & 2047;
    int d  = i / (kc * 2048);
    int srow = (n & 3) * 512 + (n >> 2);
    const float* src = in + ((size_t)d * 2048 + srow) * K + (size_t)k8 * 8;
    unsigned short* dst = out + ((size_t)d * 2048 + n) * K + (size_t)k8 * 8;
    #pragma unroll
    for (int q = 0; q < 8; ++q) dst[q] = f2bf(src[q]);
}

__global__ __launch_bounds__(256) void pack_bias_kernel(
    const float* __restrict__ bih, const float* __restrict__ bhh, float* __restrict__ out)
{
    int i = blockIdx.x * 256 + threadIdx.x;   // 4096
    if (i >= 4096) return;
    int d = i >> 11, n = i & 2047;
    int s = d * 2048 + (n & 3) * 512 + (n >> 2);
    out[i] = bih[s] + bhh[s];
}

// ---------------------------------------------------------------------------
// Dense polls — wave0 only; caller does __syncthreads() after.
// ---------------------------------------------------------------------------
template<int XPRE>
__device__ __forceinline__ void poll_l0(const unsigned* flags, int d, int tile,
                                        unsigned traw, unsigned twar,
                                        unsigned tA, unsigned tB, int l)
{
    const unsigned* pd = flags + FSLOT(d, l & 31);
    const unsigned* pw = flags + FSLOT((l < 32) ? 2 : 3, l & 31);
    const unsigned* px = flags + 512 + (((d*32 + tile)*2 + (l & 1)) << 2);
    const unsigned tx = (l & 1) ? tB : tA;
    for (;;) {
        unsigned a = ldf(pd);
        unsigned b = ldf(pw);
        unsigned c = XPRE ? ldf(px) : 0xFFFFFFFFu;
        cwait0();
        bool ok = (a >= traw) && (b >= twar) && (l >= 2 || c >= tx);
        if (__all((int)ok)) break;
        __builtin_amdgcn_s_sleep(1);
    }
}
__device__ __forceinline__ void poll_l1(const unsigned* flags, int d,
                                        unsigned k, int l)
{
    const unsigned* po = flags + FSLOT(2 + d, l & 31);
    const unsigned* pc = flags + FSLOT((l < 32) ? 0 : 1, l & 31);
    const unsigned town = k - 1u;
    for (;;) {
        unsigned a = ldf(po);
        unsigned b = ldf(pc);
        cwait0();
        if (__all((int)(a >= town && b >= k))) break;
        __builtin_amdgcn_s_sleep(1);
    }
}

// ---------------------------------------------------------------------------
// L0 h-cell consumer + batched xp read (34 loads, single drain)
// ---------------------------------------------------------------------------
template<int XPRE>
__device__ __forceinline__ void hcell_l0(const void* hp, const void* xpp,
    const char* ldsrow, int rotofs, f32x16& a0, f32x16& a1,
    bf16x8& xpa, bf16x8& xpb)
{
    uint4 hv[32], xv0, xv1;
    if (XPRE) {
        xv0 = cld16(xpp);
        xv1 = cld16((const char*)xpp + 16);
    }
#pragma unroll
    for (int m = 0; m < 32; ++m)
        hv[m] = cld16((const char*)hp + (size_t)m * 1024);
    cwait0();
    if (XPRE) { xpa = u2b(xv0); xpb = u2b(xv1); }
#pragma unroll
    for (int m = 0; m < 32; ++m) {
        int o = (m*32 + rotofs) & 1023;
        bf16x8 b = *(const bf16x8*)(ldsrow + o);
        bf16x8 a = u2b(hv[m]);
        if (m & 1) a1 = __builtin_amdgcn_mfma_f32_32x32x16_bf16(a, b, a1, 0, 0, 0);
        else       a0 = __builtin_amdgcn_mfma_f32_32x32x16_bf16(a, b, a0, 0, 0, 0);
    }
}

// ---------------------------------------------------------------------------
// L1 pipelined mega-load helpers (16-load half-groups, counted vmcnt)
// ---------------------------------------------------------------------------
__device__ __forceinline__ void issue16(uint4* hv, const char* hpB, int mb) {
#pragma unroll
    for (int j = 0; j < 16; ++j)
        hv[j] = cld16(hpB + (size_t)(mb + j) * 1024);
}
__device__ __forceinline__ void consume16_reg(const uint4* hv, const bf16x8* wf,
                                              int mb, f32x16& a0, f32x16& a1)
{
#pragma unroll
    for (int j = 0; j < 16; ++j) {
        const int m = mb + j;
        bf16x8 a = u2b(hv[j]);
        if (m & 1) a1 = __builtin_amdgcn_mfma_f32_32x32x16_bf16(a, wf[m], a1, 0, 0, 0);
        else       a0 = __builtin_amdgcn_mfma_f32_32x32x16_bf16(a, wf[m], a0, 0, 0, 0);
    }
}
__device__ __forceinline__ void consume16_lds(const uint4* hv, const char* ldsrow,
                                              int rotofs, int mb, f32x16& a0, f32x16& a1)
{
#pragma unroll
    for (int j = 0; j < 16; ++j) {
        const int m = mb + j;
        int o = (m*32 + rotofs) & 2047;           // L1 ih rows are 2048B (pow2)
        bf16x8 b = *(const bf16x8*)(ldsrow + o);
        bf16x8 a = u2b(hv[j]);
        if (m & 1) a1 = __builtin_amdgcn_mfma_f32_32x32x16_bf16(a, b, a1, 0, 0, 0);
        else       a0 = __builtin_amdgcn_mfma_f32_32x32x16_bf16(a, b, a0, 0, 0, 0);
    }
}

// ---------------------------------------------------------------------------
// Activation + c/h-in-registers + coalesced fragment-order h store
// ---------------------------------------------------------------------------
template<bool XADD>
__device__ __forceinline__ void act_store(
    const f32x16& a0, const f32x16& a1, bf16x8 xpa, bf16x8 xpb,
    int unitg, int wm, int l, float* creg, float* hreg, ull* hq_cell)
{
    const int g  = l & 3;
    const int hi = l >> 5;
    union { bf16x8 v; unsigned short s[8]; } ua, ub;
    ua.v = xpa; ub.v = xpb;
    float gi[4], gf[4], gg[4], go[4];
#pragma unroll
    for (int r = 0; r < 16; ++r) {
        float v0 = a0[r] + a1[r];
        if (XADD) v0 += bf2f((r < 8) ? ua.s[r] : ub.s[r - 8]);
        float v1 = __shfl_xor(v0, 1);
        float v2 = __shfl_xor(v0, 2);
        float v3 = __shfl_xor(v0, 3);
        float pv[4] = {v0, v1, v2, v3};
        const int rg = r & 3, q = r >> 2;
        if (g == rg) { gi[q] = pv[rg^0]; gf[q] = pv[rg^1]; gg[q] = pv[rg^2]; go[q] = pv[rg^3]; }
    }
    const int ubase = unitg & ~3;
    ull* dst = hq_cell + wm*4096 + (ubase >> 4)*128 + ((ubase >> 3) & 1)*64
                       + ((ubase >> 2) & 1);
#pragma unroll
    for (int q = 0; q < 4; ++q) {
        int rl = g + 8*q + 4*hi;
        float cold = creg[q];
        float cnew = sigf(gf[q]) * cold + sigf(gi[q]) * tanhfast(gg[q]);
        float hnew = sigf(go[q]) * tanhfast(cnew);
        creg[q] = cnew;
        hreg[q] = hnew;
        unsigned m  = f2bf(hnew);
        unsigned o1 = __shfl_xor(m, 4);
        unsigned d0 = (unitg & 1) ? ((m << 16) | o1) : ((o1 << 16) | m);
        unsigned o2 = __shfl_xor(d0, 8);
        ull q64 = (unitg & 2) ? (((ull)d0 << 32) | (ull)o2) : (((ull)o2 << 32) | (ull)d0);
        if ((l & 12) == 0)
            HSTORE64(dst + rl*2, q64);
    }
}

// ---------------------------------------------------------------------------
// Persistent kernel. XPRE=1: 256 blocks — 64 L0, 64 L1, 128 xproj producers;
// all weight slices staged INLINE from original f32 tensors (no prep kernels).
// XPRE=0: 128 blocks (L0/L1 only, packed-buffer staging, conv_x'd xb).
// ---------------------------------------------------------------------------
template<int XPRE>
__global__ __launch_bounds__(256, 1) void persist_kernel(
    const float* __restrict__ xin,        // (S,B,E) f32
    const unsigned short* __restrict__ xb,
    const float* __restrict__ wih0f, const float* __restrict__ whh0f,
    const float* __restrict__ wih1f, const float* __restrict__ whh1f,
    const float* __restrict__ bih0,  const float* __restrict__ bhh0,
    const float* __restrict__ bih1,  const float* __restrict__ bhh1,
    const unsigned short* __restrict__ w0p,
    const unsigned short* __restrict__ wh0p,
    const unsigned short* __restrict__ w1p,
    const unsigned short* __restrict__ wh1p,
    const float* __restrict__ b0p,
    const float* __restrict__ b1p,
    unsigned short* __restrict__ xp,
    unsigned short* __restrict__ hbuf,
    float* __restrict__ cbuf,
    unsigned short* __restrict__ hplain,
    unsigned* __restrict__ flags)
{
    extern __shared__ __align__(16) char lds[];
    const int tid = threadIdx.x;
    const int l   = tid & 63;
    const int w   = tid >> 6;
    const int wm  = w & 1, wn = w >> 1;
    const int bid = blockIdx.x;
    const int lrow  = wn * 32 + (l & 31);
    const int khalf = l >> 5;
    const int HHOFF = 64 * 1280;

    // ================= PRODUCER ROLE (XPRE only, bid >= 128) ================
    if (XPRE && bid >= 128) {
        const int bid2 = bid - 128;
        const int dd   = bid2 >> 6;
        const int tile = (bid2 >> 1) & 31;
        const int half = bid2 & 1;
        const int n0p  = tile * 64;
        for (int idx = tid; idx < 64 * 80; idx += 256) {   // wih0 f32: 64 x 640
            int r = idx / 80, k8 = idx % 80;
            int srow = (((n0p + r) & 3) << 9) + ((n0p + r) >> 2);
            const float* src = wih0f + ((size_t)dd*2048 + srow)*640 + (size_t)k8*8;
            uint4 u = pk8(*(const float4*)src, *(const float4*)(src + 4));
            int o = k8*16 + r*16; o -= (o >= 1280) ? 1280 : 0;
            *(uint4*)(lds + r*1280 + o) = u;
        }
        __syncthreads();
        const char* ldsrow = lds + (size_t)lrow * 1280;
        const int rot = lrow * 16 + khalf * 16;
        const int t0 = half * 128, t1 = half ? TSTEPS : 128;
        unsigned* pxf = flags + 512 + (((dd*32 + tile)*2 + half) << 2);
        for (int t = t0; t < t1; ++t) {
            f32x16 a0, a1;
#pragma unroll
            for (int r = 0; r < 16; ++r) { a0[r] = 0.f; a1[r] = 0.f; }
            const float* Af = xin + ((size_t)t*B + wm*32 + (l & 31))*E + khalf*8;
#pragma unroll 8
            for (int k0 = 0; k0 < E; k0 += 16) {
                bf16x8 a = u2b(pk8(*(const float4*)(Af + k0), *(const float4*)(Af + k0 + 4)));
                int o = k0*2 + rot; o -= (o >= 1280) ? 1280 : 0;
                bf16x8 b = *(const bf16x8*)(ldsrow + o);
                if ((k0 >> 4) & 1) a1 = __builtin_amdgcn_mfma_f32_32x32x16_bf16(a, b, a1, 0, 0, 0);
                else               a0 = __builtin_amdgcn_mfma_f32_32x32x16_bf16(a, b, a0, 0, 0, 0);
            }
            size_t base = ((((size_t)t*2 + dd)*64 + tile*2 + wn)*2 + wm)*1024 + (size_t)l*16;
            ull* dst = (ull*)(xp + base);
            union { uint4 v; ull q[2]; } c0, c1;
            c0.v.x = pk2(a0[0]+a1[0],  a0[1]+a1[1]);
            c0.v.y = pk2(a0[2]+a1[2],  a0[3]+a1[3]);
            c0.v.z = pk2(a0[4]+a1[4],  a0[5]+a1[5]);
            c0.v.w = pk2(a0[6]+a1[6],  a0[7]+a1[7]);
            c1.v.x = pk2(a0[8]+a1[8],  a0[9]+a1[9]);
            c1.v.y = pk2(a0[10]+a1[10], a0[11]+a1[11]);
            c1.v.z = pk2(a0[12]+a1[12], a0[13]+a1[13]);
            c1.v.w = pk2(a0[14]+a1[14], a0[15]+a1[15]);
            HSTORE64(dst + 0, c0.q[0]); HSTORE64(dst + 1, c0.q[1]);
            HSTORE64(dst + 2, c1.q[0]); HSTORE64(dst + 3, c1.q[1]);
            asm volatile("s_waitcnt vmcnt(0)" ::: "memory");
            __syncthreads();
            if (tid == 0) HSTORE32(pxf, (unsigned)(t - t0 + 1));
        }
        return;
    }

    // ================= RECURRENCE ROLES =====================================
    const bool isL1 = bid >= 64;
    const int g2 = bid & 63;
    const int d  = g2 >> 5;
    const int n0 = (g2 & 31) * 64;
    const int myslot = g2 & 31;
    const int tile   = g2 & 31;

    if (XPRE) {
        if (!isL1) {
            for (int idx = tid; idx < 64 * 64; idx += 256) {   // whh0 f32: 64 x 512
                int r = idx >> 6, k8 = idx & 63;
                int srow = (((n0 + r) & 3) << 9) + ((n0 + r) >> 2);
                const float* src = whh0f + ((size_t)d*2048 + srow)*512 + (size_t)k8*8;
                uint4 u = pk8(*(const float4*)src, *(const float4*)(src + 4));
                int o = (k8*16 + r*16) & 1023;
                *(uint4*)(lds + r*1024 + o) = u;
            }
        } else {
            for (int idx = tid; idx < 64 * 128; idx += 256) {  // wih1 f32: 64 x 1024
                int r = idx >> 7, k8 = idx & 127;
                int srow = (((n0 + r) & 3) << 9) + ((n0 + r) >> 2);
                const float* src = wih1f + ((size_t)d*2048 + srow)*1024 + (size_t)k8*8;
                uint4 u = pk8(*(const float4*)src, *(const float4*)(src + 4));
                int o = (k8*16 + r*16) & 2047;
                *(uint4*)(lds + r*2048 + o) = u;
            }
        }
    } else {
        if (!isL1) {
            for (int idx = tid; idx < 64 * 80; idx += 256) {
                int r = idx / 80, k8 = idx % 80;
                bf16x8 v = *(const bf16x8*)(w0p + ((size_t)d*2048 + n0 + r)*640 + (size_t)k8*8);
                int o = k8*16 + r*16; o -= (o >= 1280) ? 1280 : 0;
                *(bf16x8*)(lds + r*1280 + o) = v;
            }
            for (int idx = tid; idx < 64 * 64; idx += 256) {
                int r = idx / 64, k8 = idx % 64;
                bf16x8 v = *(const bf16x8*)(wh0p + ((size_t)d*2048 + n0 + r)*512 + (size_t)k8*8);
                int o = k8*16 + r*16; o -= (o >= 1024) ? 1024 : 0;
                *(bf16x8*)(lds + HHOFF + r*1024 + o) = v;
            }
        } else {
            for (int idx = tid; idx < 64 * 128; idx += 256) {
                int r = idx / 128, k8 = idx % 128;
                bf16x8 v = *(const bf16x8*)(w1p + ((size_t)d*2048 + n0 + r)*1024 + (size_t)k8*8);
                int o = k8*16 + r*16; o -= (o >= 2048) ? 2048 : 0;
                *(bf16x8*)(lds + r*2048 + o) = v;
            }
        }
    }
    __syncthreads();

    const int srowg = (((n0 + lrow) & 3) << 9) + ((n0 + lrow) >> 2);
    const float bias = XPRE
        ? (isL1 ? (bih1[d*2048 + srowg] + bhh1[d*2048 + srowg])
                : (bih0[d*2048 + srowg] + bhh0[d*2048 + srowg]))
        : (isL1 ? b1p : b0p)[d*2048 + n0 + lrow];
    const char* ldsrow_ih = lds + (size_t)lrow * (isL1 ? 2048 : 1280);
    const char* ldsrow_hh = lds + (XPRE ? 0 : HHOFF) + (size_t)lrow * 1024;
    const int rot = lrow * 16 + khalf * 16;
    const int unitg = ((n0 + lrow) >> 2);
    const int hoff  = wm*4096 + khalf*64 + (l & 31)*2;     // u64 units
    const int arow  = wm * 32 + (l & 31);
    float creg[4] = {0.f, 0.f, 0.f, 0.f};
    float hreg[4] = {0.f, 0.f, 0.f, 0.f};
    const ull* hb = (const ull*)hbuf;
    ull*       hw = (ull*)hbuf;
    const int mycell = isL1 ? (2 + d) : d;
    unsigned* myflag = flags + FSLOT(mycell, myslot);
    bf16x8 zero8 = {};

    bf16x8 wh[32];     // L1: own-cell hidden weights in VGPR
    if (isL1) {
        if (XPRE) {
            const float* whl = whh1f + ((size_t)d*2048 + srowg)*512 + khalf*8;
#pragma unroll
            for (int m = 0; m < 32; ++m)
                wh[m] = u2b(pk8(*(const float4*)(whl + m*16), *(const float4*)(whl + m*16 + 4)));
        } else {
            const unsigned short* whl = wh1p + ((size_t)d*2048 + n0 + lrow)*512 + khalf*8;
#pragma unroll
            for (int m = 0; m < 32; ++m) wh[m] = *(const bf16x8*)(whl + m*16);
        }
    }

    for (int k = 0; k <= TSTEPS; ++k) {
        const int rbuf = k % NBUF, wbuf = (k + 1) % NBUF;
        const size_t rb = (size_t)rbuf * 4 * CELL64;
        const size_t wb = (size_t)wbuf * 4 * CELL64;
        if (!isL1) {
            if (k < TSTEPS) {
                f32x16 a0, a1;
#pragma unroll
                for (int r = 0; r < 16; ++r) { a0[r] = bias; a1[r] = 0.f; }
                bf16x8 xpa = zero8, xpb = zero8;
                if (!XPRE) {
                    const unsigned short* Ax = xb + (size_t)k*B*E + (size_t)arow*E + khalf*8;
#pragma unroll 8
                    for (int k0 = 0; k0 < E; k0 += 16) {
                        bf16x8 a = *(const bf16x8*)(Ax + k0);
                        int o = k0*2 + rot; o -= (o >= 1280) ? 1280 : 0;
                        bf16x8 b = *(const bf16x8*)(ldsrow_ih + o);
                        if ((k0 >> 4) & 1) a1 = __builtin_amdgcn_mfma_f32_32x32x16_bf16(a, b, a1, 0, 0, 0);
                        else               a0 = __builtin_amdgcn_mfma_f32_32x32x16_bf16(a, b, a0, 0, 0, 0);
                    }
                }
                {
                    unsigned tA = XPRE ? ((k < 128) ? (unsigned)(k + 1) : 128u) : 0u;
                    unsigned tB = XPRE ? ((k < 128) ? 0u : (unsigned)(k - 127)) : 0u;
                    unsigned traw = (k >= 1) ? (unsigned)k : 0u;
                    unsigned twar = (k >= 3) ? (unsigned)(k - 3) : 0u;
                    if (XPRE || k >= 1) {
                        if (w == 0) poll_l0<XPRE>(flags, d, tile, traw, twar, tA, tB, l);
                        __syncthreads();
                    }
                }
                const char* xpp = (const char*)xp +
                    (((((size_t)k*2 + d)*64 + tile*2 + wn)*2 + wm)*1024 + (size_t)l*16) * 2;
                hcell_l0<XPRE>((const char*)(hb + rb + (size_t)d*CELL64 + hoff), xpp,
                               ldsrow_hh, rot, a0, a1, xpa, xpb);
                act_store<true>(a0, a1, xpa, xpb, unitg, wm, l, creg, hreg,
                                hw + wb + (size_t)d*CELL64);
                asm volatile("s_waitcnt vmcnt(0)" ::: "memory");
                __syncthreads();                       // all waves' stores acked
                if (tid == 0) HSTORE32(myflag, (unsigned)(k + 1));
            }
        } else {
            if (k >= 1) {
                f32x16 a0, a1;
#pragma unroll
                for (int r = 0; r < 16; ++r) { a0[r] = bias; a1[r] = 0.f; }
                if (w == 0) poll_l1(flags, d, (unsigned)k, l);
                __syncthreads();
                const char* hpO = (const char*)(hb + rb + (size_t)(2+d)*CELL64 + hoff);
                const char* hp0 = (const char*)(hb + rb + (size_t)0*CELL64 + hoff);
                const char* hp1 = (const char*)(hb + rb + (size_t)1*CELL64 + hoff);
                uint4 hvA[16], hvB[16];
                issue16(hvA, hpO, 0);
                issue16(hvB, hpO, 16);
                vmw16(); consume16_reg(hvA, wh, 0,  a0, a1);
                issue16(hvA, hp0, 0);
                vmw16(); consume16_reg(hvB, wh, 16, a0, a1);
                issue16(hvB, hp0, 16);
                vmw16(); consume16_lds(hvA, ldsrow_ih, rot, 0,  a0, a1);
                issue16(hvA, hp1, 0);
                vmw16(); consume16_lds(hvB, ldsrow_ih, rot, 16, a0, a1);
                issue16(hvB, hp1, 16);
                vmw16(); consume16_lds(hvA, ldsrow_ih, rot + 1024, 0,  a0, a1);
                cwait0(); consume16_lds(hvB, ldsrow_ih, rot + 1024, 16, a0, a1);
                act_store<false>(a0, a1, zero8, zero8, unitg, wm, l, creg, hreg,
                                 hw + wb + (size_t)(2+d)*CELL64);
                asm volatile("s_waitcnt vmcnt(0)" ::: "memory");
                __syncthreads();
                if (tid == 0) HSTORE32(myflag, (unsigned)k);
            }
        }
    }

    {
        float*          cc = cbuf   + (size_t)mycell * HS;
        unsigned short* hh = hplain + (size_t)mycell * HS;
        const int g = l & 3, hi = l >> 5;
#pragma unroll
        for (int q = 0; q < 4; ++q) {
            int row = 32*wm + g + 8*q + 4*hi;
            cc[(size_t)row * 512 + unitg] = creg[q];
            hh[(size_t)row * 512 + unitg] = f2bf(hreg[q]);
        }
    }
}

// ---------------------------------------------------------------------------
// Head (unchanged)
// ---------------------------------------------------------------------------
__global__ __launch_bounds__(256) void head_kernel(
    const unsigned short* __restrict__ hplain,
    const float* __restrict__ cbuf,
    const float* __restrict__ eps,
    const float* __restrict__ Wmu,  const float* __restrict__ bmu,
    const float* __restrict__ Wvar, const float* __restrict__ bvar,
    float* __restrict__ out)
{
    const int tid = threadIdx.x;
    const int b   = tid & 63;
    const int i   = blockIdx.x * 4 + (tid >> 6);

    __shared__ float zs[KT][B + 1];

    float amu = 0.f, alv = 0.f;
    const float* wm = Wmu  + (size_t)i * ZDIM;
    const float* wv = Wvar + (size_t)i * ZDIM;

    for (int k0 = 0; k0 < ZDIM; k0 += KT) {
        __syncthreads();
        for (int idx = tid; idx < (B * KT) / 4; idx += 256) {
            int bb  = idx / (KT / 4);
            int kq4 = (idx % (KT / 4)) * 4;
            int zk  = k0 + kq4;
            int cell = zk >> 10;
            int m    = zk & 1023;
            float4 v;
            if (m < H) {
                const unsigned short* hs = hplain + (size_t)cell * HS + (size_t)bb * H + m;
                v.x = bf2f(hs[0]); v.y = bf2f(hs[1]); v.z = bf2f(hs[2]); v.w = bf2f(hs[3]);
            } else {
                v = *(const float4*)(cbuf + (size_t)cell * HS + (size_t)bb * H + (m - H));
            }
            zs[kq4 + 0][bb] = v.x; zs[kq4 + 1][bb] = v.y;
            zs[kq4 + 2][bb] = v.z; zs[kq4 + 3][bb] = v.w;
        }
        __syncthreads();
        #pragma unroll
        for (int kk = 0; kk < KT; kk += 4) {
            float4 a = *(const float4*)(wm + k0 + kk);
            float4 c = *(const float4*)(wv + k0 + kk);
            float z0 = zs[kk + 0][b], z1 = zs[kk + 1][b];
            float z2 = zs[kk + 2][b], z3 = zs[kk + 3][b];
            amu += a.x * z0 + a.y * z1 + a.z * z2 + a.w * z3;
            alv += c.x * z0 + c.y * z1 + c.z * z2 + c.w * z3;
        }
    }
    float mu = amu + bmu[i];
    float lv = alv + bvar[i];
    out[(size_t)b * ZDIM + i] = mu + eps[(size_t)b * ZDIM + i] * __expf(0.5f * lv);
}

// ---------------------------------------------------------------------------
extern "C" void kernel_launch(void* const* d_in, const int* in_sizes, int n_in,
                              void* d_out, int out_size, void* d_ws, size_t ws_size,
                              hipStream_t stream) {
    const float* input = (const float*)d_in[0];
    const float* eps   = (const float*)d_in[1];
    const float* w_ih0 = (const float*)d_in[2];
    const float* w_hh0 = (const float*)d_in[3];
    const float* b_ih0 = (const float*)d_in[4];
    const float* b_hh0 = (const float*)d_in[5];
    const float* w_ih1 = (const float*)d_in[6];
    const float* w_hh1 = (const float*)d_in[7];
    const float* b_ih1 = (const float*)d_in[8];
    const float* b_hh1 = (const float*)d_in[9];
    const float* W_mu  = (const float*)d_in[10];
    const float* b_mu  = (const float*)d_in[11];
    const float* W_var = (const float*)d_in[12];
    const float* b_var = (const float*)d_in[13];
    float* out = (float*)d_out;

    uint8_t* base = (uint8_t*)d_ws;
    size_t off = 0;
    auto alloc = [&](size_t bytes) -> void* {
        void* p = base + off;
        off += (bytes + 255) & ~(size_t)255;
        return p;
    };
    unsigned short* xb   = (unsigned short*)alloc((size_t)TSTEPS * B * E * 2);
    unsigned short* w0p  = (unsigned short*)alloc((size_t)2 * 2048 * E * 2);
    unsigned short* wh0p = (unsigned short*)alloc((size_t)2 * 2048 * H * 2);
    unsigned short* w1p  = (unsigned short*)alloc((size_t)2 * 2048 * 1024 * 2);
    unsigned short* wh1p = (unsigned short*)alloc((size_t)2 * 2048 * H * 2);
    float* b0p = (float*)alloc(2 * 2048 * 4);
    float* b1p = (float*)alloc(2 * 2048 * 4);
    unsigned* flags      = (unsigned*)alloc(4096);      // cells 2KB + producers 2KB
    unsigned short* hbuf = (unsigned short*)alloc((size_t)NBUF * 4 * HS * 2);
    float* cbuf          = (float*)alloc((size_t)4 * HS * 4);
    unsigned short* hplain = (unsigned short*)alloc((size_t)4 * HS * 2);
    unsigned short* xp   = (unsigned short*)alloc((size_t)TSTEPS * 2 * 2048 * B * 2); // 134MB
    const bool XPRE = (ws_size >= off);

    // zero flags + h (NBUF bufs)
    hipMemsetAsync(flags, 0, 4096 + (size_t)NBUF * 4 * HS * 2, stream);

    const size_t lds_persist = 144 * 1024;
    if (XPRE) {
        hipFuncSetAttribute((const void*)persist_kernel<1>,
                            hipFuncAttributeMaxDynamicSharedMemorySize, (int)lds_persist);
        persist_kernel<1><<<256, 256, lds_persist, stream>>>(
            input, xb, w_ih0, w_hh0, w_ih1, w_hh1, b_ih0, b_hh0, b_ih1, b_hh1,
            w0p, wh0p, w1p, wh1p, b0p, b1p, xp, hbuf, cbuf, hplain, flags);
    } else {
        conv_x_kernel<<<(TSTEPS * B * E / 8 + 255) / 256, 256, 0, stream>>>(
            input, xb, TSTEPS * B * E / 8);
        repack_w_kernel<<<(2 * 2048 * (E / 8) + 255) / 256, 256, 0, stream>>>(w_ih0, w0p, E);
        repack_w_kernel<<<(2 * 2048 * (H / 8) + 255) / 256, 256, 0, stream>>>(w_hh0, wh0p, H);
        repack_w_kernel<<<(2 * 2048 * (1024 / 8) + 255) / 256, 256, 0, stream>>>(w_ih1, w1p, 1024);
        repack_w_kernel<<<(2 * 2048 * (H / 8) + 255) / 256, 256, 0, stream>>>(w_hh1, wh1p, H);
        pack_bias_kernel<<<16, 256, 0, stream>>>(b_ih0, b_hh0, b0p);
        pack_bias_kernel<<<16, 256, 0, stream>>>(b_ih1, b_hh1, b1p);
        hipFuncSetAttribute((const void*)persist_kernel<0>,
                            hipFuncAttributeMaxDynamicSharedMemorySize, (int)lds_persist);
        persist_kernel<0><<<128, 256, lds_persist, stream>>>(
            input, xb, w_ih0, w_hh0, w_ih1, w_hh1, b_ih0, b_hh0, b_ih1, b_hh1,
            w0p, wh0p, w1p, wh1p, b0p, b1p, xp, hbuf, cbuf, hplain, flags);
    }

    head_kernel<<<ZDIM / 4, 256, 0, stream>>>(hplain, cbuf, eps, W_mu, b_mu, W_var, b_var, out);
}